// Round 19
// baseline (32.877 us; speedup 1.0000x reference)
//
#include <hip/hip_runtime.h>
#include <math.h>

#define NP 30      // points per cloud
#define KNN 20     // neighbors
#define KS 5       // spline control points
#define FN 10      // filter count
#define EPS 1e-8f
#define CPB 16     // clouds per block (fills the 16-row MFMA A-tile)
#define T1 512     // block size (8 waves)

typedef __attribute__((ext_vector_type(8))) short short8v;
typedef __attribute__((ext_vector_type(4))) float float4v;

__device__ __forceinline__ float satf(float x) {
    return fminf(fmaxf(x, 0.0f), 1.0f);   // folds to clamp modifier
}
__device__ __forceinline__ unsigned short bf16r(float f) {   // f32 -> bf16 RNE
    unsigned u = __float_as_uint(f);
    u += 0x7fffu + ((u >> 16) & 1u);
    return (unsigned short)(u >> 16);
}
// hA swizzle: 16B granule g of row r -> g ^ (r&7); kills stride-512B conflicts
__device__ __forceinline__ int hA_idx(int row, int col) {
    return row * 256 + ((((col >> 3) ^ (row & 7)) << 3) | (col & 7));
}
// pack point index into low 5 mantissa bits (sort stays float-compare)
__device__ __forceinline__ float packdi(float v, int j) {
    return __uint_as_float((__float_as_uint(v) & ~31u) | (unsigned)j);
}

// compare-exchange helpers (ascending / descending)
#define CEA(A, B) { float a_ = vals[A], b_ = vals[B]; vals[A] = fminf(a_, b_); vals[B] = fmaxf(a_, b_); }
#define CED(A, B) { float a_ = vals[A], b_ = vals[B]; vals[A] = fmaxf(a_, b_); vals[B] = fminf(a_, b_); }

// Fused dsc -> MLP -> log_softmax. One 512-thread block = 16 clouds.
// R19: (a) revert to launch_bounds(512,4) (r18's 6-waves was neutral-worse);
// (b) G,s cloud sums computed by the 32 PERMANENTLY IDLE threads (480-511)
// directly from ptsF, overlapped with the sort -> deletes the outer-product
// LDS staging (3 ds_writes/thread), the 144-thread reduce phase, and one
// barrier. Summation order unchanged -> bit-identical numerics.
__global__ __launch_bounds__(T1, 4) void fused_kernel(
    const float* __restrict__ pos,     // [B*NP, 3]
    const float* __restrict__ W,       // [KS, FN]
    const float* __restrict__ b_dsc,   // [FN]
    const float* __restrict__ w1,      // [FN, 256]
    const float* __restrict__ b1,      // [256]
    const float* __restrict__ w2,      // [256, 40]
    const float* __restrict__ b2,      // [40]
    float* __restrict__ out,           // [B, 40]
    int B)
{
    __shared__ float4 ptsF[CPB * NP];                       // x,y,z,|p|^2
    __shared__ __align__(16) float sb[CPB * NP][12];        // sigmoid staging
    __shared__ __align__(16) float Gs[CPB][12];             // gxx..gzz sx sy sz
    __shared__ __align__(16) unsigned short ysbf[CPB * 40]; // bf16 ys A-tile, K-pad 40
    __shared__ __align__(16) unsigned short hA[16 * 256];   // bf16 A-tile (layer 2)
    __shared__ float Lg[CPB][48];

    const int tid  = threadIdx.x;
    const int base = blockIdx.x * CPB;
    const int w    = tid >> 6;
    const int lane = tid & 63;

    // stage: one point per thread (xyz + |p|^2)
    if (tid < CPB * NP) {
        int gp = base * NP + tid;
        if (gp < B * NP) {
            const float* pp = pos + (size_t)gp * 3;
            float x = pp[0], y = pp[1], z = pp[2];
            float n2 = fmaf(z, z, fmaf(y, y, x * x));
            ptsF[tid] = make_float4(x, y, z, n2);
        } else {
            ptsF[tid] = make_float4(0.f, 0.f, 0.f, 0.f);
        }
    }
    // zero ysbf (640 u16 = 320 u32); reduce overwrites f<10 slots later
    if (tid < 320) ((unsigned*)ysbf)[tid] = 0u;
    __syncthreads();                                              // S1

    const int c = tid / NP;
    const int i = tid - c * NP;
    const bool active = (tid < CPB * NP) && (base + c < B);

    float vals[32];
    float ox = 0.f, oy = 0.f, oz = 0.f, oo = 0.f;

    if (active) {
        const float4* cp = &ptsF[c * NP];
        float4 own = cp[i];                       // dynamic LDS read, once
        ox = own.x; oy = own.y; oz = own.z; oo = own.w;

        // keys: key_j = n2_j - 2 p_j.o  (3-fma form; monotone shift of d2)
        const float nx2 = -2.0f * ox, ny2 = -2.0f * oy, nz2 = -2.0f * oz;
        #pragma unroll
        for (int j = 0; j < NP; ++j) {
            float4 q = cp[j];
            float key = fmaf(q.z, nz2, fmaf(q.y, ny2, fmaf(q.x, nx2, q.w)));
            vals[j] = packdi(key, j);
            if ((j % 5) == 4) asm volatile("" ::: "memory");  // bound in-flight loads
        }
        vals[30] = packdi(1e11f, 30);
        vals[31] = packdi(1e11f, 31);

        // --- Batcher odd-even mergesort: lower 16 asc, upper 16 desc ---
        #pragma unroll
        for (int p = 1; p < 16; p <<= 1) {
            #pragma unroll
            for (int k = p; k >= 1; k >>= 1) {
                #pragma unroll
                for (int j = (k & (p - 1)); j + k < 16; j += 2 * k) {
                    #pragma unroll
                    for (int ii = 0; ii < k; ++ii) {
                        if (ii + j + k < 16 &&
                            ((ii + j) / (2 * p)) == ((ii + j + k) / (2 * p))) {
                            CEA(ii + j, ii + j + k);
                            CED(16 + ii + j, 16 + ii + j + k);
                        }
                    }
                }
            }
        }
        // --- bitonic k=32 split: BOTH sides (lower = 16-smallest SET) ---
        #pragma unroll
        for (int q = 0; q < 16; ++q) { CEA(q, 16 + q); }
        // --- bitonic merge of upper 16, pruned to the cone of 20..29 ---
        #pragma unroll
        for (int q = 0; q < 8; ++q) { CEA(16 + q, 24 + q); }
        CEA(16, 20) CEA(17, 21) CEA(18, 22) CEA(19, 23)
        CEA(24, 28) CEA(25, 29) CEA(26, 30) CEA(27, 31)
        CEA(20, 22) CEA(21, 23) CEA(24, 26) CEA(25, 27) CEA(28, 30) CEA(29, 31)
        CEA(20, 21) CEA(22, 23) CEA(24, 25) CEA(26, 27) CEA(28, 29)
    } else if (tid >= CPB * NP) {
        // --- G,s cloud sums on the 32 idle threads, overlapped with sort ---
        // role 0: Gs[cc][0..3] = sum(x*x, x*y, x*z, y*y)
        // role 1: Gs[cc][4..7] = sum(y*z, z*z, x, y); Gs[cc][8] = sum(z)
        int r    = tid - CPB * NP;      // 0..31
        int cc   = r & 15;
        int role = r >> 4;
        const float4* cq = &ptsF[cc * NP];
        float s0 = 0.f, s1r = 0.f, s2 = 0.f, s3 = 0.f, s4 = 0.f;
        #pragma unroll 5
        for (int k = 0; k < NP; ++k) {
            float4 q = cq[k];
            if (role == 0) {
                s0 = fmaf(q.x, q.x, s0); s1r = fmaf(q.x, q.y, s1r);
                s2 = fmaf(q.x, q.z, s2); s3 = fmaf(q.y, q.y, s3);
            } else {
                s0 = fmaf(q.y, q.z, s0); s1r = fmaf(q.z, q.z, s1r);
                s2 += q.x; s3 += q.y; s4 += q.z;
            }
        }
        *(float4*)&Gs[cc][role * 4] = make_float4(s0, s1r, s2, s3);
        if (role == 1) Gs[cc][8] = s4;
    }
    __syncthreads();                                              // S2

    if (active) {
        const float4* cp = &ptsF[c * NP];
        const float thr_key = __uint_as_float(__float_as_uint(vals[20]) & ~31u);
        const float thr_d2  = thr_key + oo;                 // rank-20 d2
        const float scale   = sqrtf(thr_d2 + EPS) + EPS;
        const float inv_s   = __builtin_amdgcn_rcpf(scale);

        // cov of ALL 30 rels from cloud G,s:  C = G - s o^T - o s^T + 30 o o^T
        float4 g0 = *(const float4*)&Gs[c][0];   // gxx gxy gxz gyy
        float4 g1 = *(const float4*)&Gs[c][4];   // gyz gzz sx  sy
        float  sx = g1.z, sy = g1.w, sz = Gs[c][8];
        float ax = fmaf(30.f, ox, -sx);
        float ay = fmaf(30.f, oy, -sy);
        float az = fmaf(30.f, oz, -sz);
        float cxx = fmaf(ox, ax, fmaf(-sx, ox, g0.x));
        float cxy = fmaf(oy, ax, fmaf(-sy, ox, g0.y));
        float cxz = fmaf(oz, ax, fmaf(-sz, ox, g0.z));
        float cyy = fmaf(oy, ay, fmaf(-sy, oy, g0.w));
        float cyz = fmaf(oz, ay, fmaf(-sz, oy, g1.x));
        float czz = fmaf(oz, az, fmaf(-sz, oz, g1.y));

        // subtract the 9 excluded outer products (ranks 21..29, sorted upper)
        #pragma unroll
        for (int q2 = 21; q2 < 30; ++q2) {
            int idx = (int)(__float_as_uint(vals[q2]) & 31u);
            float4 p = cp[idx];
            float dx = p.x - ox, dy = p.y - oy, dz = p.z - oz;
            cxx = fmaf(-dx, dx, cxx); cxy = fmaf(-dx, dy, cxy); cxz = fmaf(-dx, dz, cxz);
            cyy = fmaf(-dy, dy, cyy); cyz = fmaf(-dy, dz, cyz); czz = fmaf(-dz, dz, czz);
        }

        // power iteration x8 == C^8 v0: trace-norm + 3 symmetric squarings
        float tr = cxx + cyy + czz + 1e-30f;
        float rt = __builtin_amdgcn_rcpf(tr);
        float xx = cxx*rt, xy = cxy*rt, xz = cxz*rt;
        float yy = cyy*rt, yz = cyz*rt, zz = czz*rt;
        #pragma unroll
        for (int it = 0; it < 3; ++it) {
            float nxx = fmaf(xx, xx, fmaf(xy, xy, xz * xz));
            float nxy = fmaf(xy, xx + yy, xz * yz);
            float nxz = fmaf(xz, xx + zz, xy * yz);
            float nyy = fmaf(xy, xy, fmaf(yy, yy, yz * yz));
            float nyz = fmaf(yz, yy + zz, xy * xz);
            float nzz = fmaf(xz, xz, fmaf(yz, yz, zz * zz));
            xx = nxx; xy = nxy; xz = nxz; yy = nyy; yz = nyz; zz = nzz;
        }
        float vx = xx + xy + xz;
        float vy = xy + yy + yz;
        float vz = xz + yz + zz;
        float nn = fmaf(vz, vz, fmaf(vy, vy, vx * vx)) + 1e-30f;
        float rr2 = __builtin_amdgcn_rsqf(nn) * inv_s * 2.0f;
        const float wax = vx * rr2, way = vy * rr2, waz = vz * rr2;
        const float c0  = 2.0f - fmaf(oz, waz, fmaf(oy, way, ox * wax));

        // pass B over the 21 SELECTED points: vals[0..15] = 16-nearest set,
        // vals[16..20] = ranks 16..20. Self among them, u ~= 2 (subtracted).
        float a0 = 0.f, a1 = 0.f, a3 = 0.f, s1 = 0.f;
        #pragma unroll
        for (int q = 0; q < 21; ++q) {
            int idx = (int)(__float_as_uint(vals[q]) & 31u);
            float4 p = cp[idx];
            float ur = fmaf(p.z, waz, fmaf(p.y, way, fmaf(p.x, wax, c0)));
            a0 += satf(1.0f - ur);               // ur >= -eps: no abs needed
            a1 += satf(1.0f - fabsf(ur - 1.0f));
            a3 += satf(1.0f - fabsf(ur - 3.0f));
            s1 += ur;
            if ((q % 5) == 4) asm volatile("" ::: "memory");
        }
        const float P  = 21.0f - a0 - a1 - a3;   // a2 + a4
        const float Q  = s1 - a1 - 3.0f * a3;    // 2*a2 + 4*a4
        const float a4 = fmaf(0.5f, Q, -P);
        const float a2 = P - a4 - 1.0f;          // self sits at u=2

        // sigmoid via exp2; W/b_dsc uniform scalar loads (SGPR operands)
        #pragma unroll
        for (int f = 0; f < FN; ++f) {
            float acc = fmaf(a0, W[0*FN+f],
                        fmaf(a1, W[1*FN+f],
                        fmaf(a2, W[2*FN+f],
                        fmaf(a3, W[3*FN+f],
                             a4 * W[4*FN+f]))));
            float bn = b_dsc[f] * (-1.4426950408889634f);        // -log2e * b
            float z2 = fmaf(acc, -0.07213475204444817f, bn);     // -log2e/20
            sb[tid][f] = __builtin_amdgcn_rcpf(1.0f + exp2f(z2));
        }
    }
    __syncthreads();                                              // S3

    // ys reduce (tid<160) -> bf16 into the zero-padded A-tile
    if (tid < CPB * FN) {
        int c2 = tid / FN;
        int f  = tid - c2 * FN;
        float s = 0.0f;
        #pragma unroll
        for (int jj = 0; jj < NP; ++jj) s += sb[c2 * NP + jj][f];
        float ym = (base + c2 < B) ? s * (1.0f / (float)NP) : 0.0f;
        ysbf[c2 * 40 + f] = bf16r(ym);
    }
    __syncthreads();                                              // S4

    // layer 1 via MFMA: h[16][256] = ys[16][10pad32] @ w1[10][256] + b1; elu.
    {
        const int kg = (lane >> 4) * 8;
        short8v a = *(const short8v*)&ysbf[(lane & 15) * 40 + kg];
        #pragma unroll
        for (int t2 = 0; t2 < 2; ++t2) {
            const int n = (w * 2 + t2) * 16 + (lane & 15);
            short8v bfr;
            #pragma unroll
            for (int j = 0; j < 8; ++j) {
                int k = kg + j;
                float f = (k < FN) ? w1[k * 256 + n] : 0.0f;
                bfr[j] = (short)bf16r(f);
            }
            float4v acc = {0.f, 0.f, 0.f, 0.f};
            acc = __builtin_amdgcn_mfma_f32_16x16x32_bf16(a, bfr, acc, 0, 0, 0);
            const float bb = b1[n];
            #pragma unroll
            for (int r = 0; r < 4; ++r) {
                int cl = (lane >> 4) * 4 + r;
                float h = acc[r] + bb;
                h = h > 0.0f ? h : __expf(h) - 1.0f;
                hA[hA_idx(cl, n)] = bf16r(h);
            }
        }
    }
    __syncthreads();                                              // S5

    // layer 2: waves 0..2 each own one 16-col N-tile; B-frags global->regs.
    if (w < 3) {
        const int  n   = w * 16 + (lane & 15);
        const bool nok = n < 40;
        const int  kg  = (lane >> 4) * 8;
        float4v acc = {0.f, 0.f, 0.f, 0.f};
        #pragma unroll
        for (int s = 0; s < 8; ++s) {
            short8v bfr;
            #pragma unroll
            for (int j = 0; j < 8; ++j) {
                float f = nok ? w2[(s * 32 + kg + j) * 40 + n] : 0.0f;
                bfr[j] = (short)bf16r(f);
            }
            short8v a = *(const short8v*)&hA[hA_idx(lane & 15, kg + s * 32)];
            acc = __builtin_amdgcn_mfma_f32_16x16x32_bf16(a, bfr, acc, 0, 0, 0);
        }
        // C/D: col=lane&15 (our n), row=(lane>>4)*4+r  [m89-verified]
        if (nok) {
            const float bc = b2[n];
            const int   r0 = (lane >> 4) * 4;
            #pragma unroll
            for (int r = 0; r < 4; ++r) {
                Lg[r0 + r][n] = acc[r] + bc;
            }
        }
    }
    __syncthreads();                                              // S6

    // log_softmax: 16-lane group per cloud (tid<256)
    if (tid < CPB * 16) {
        int cl = tid >> 4, l = tid & 15;
        float v0 = Lg[cl][l];
        float v1 = Lg[cl][l + 16];
        float v2 = (l < 8) ? Lg[cl][l + 32] : -INFINITY;
        float m = fmaxf(fmaxf(v0, v1), v2);
        #pragma unroll
        for (int msk = 1; msk < 16; msk <<= 1) m = fmaxf(m, __shfl_xor(m, msk));
        float e = __expf(v0 - m) + __expf(v1 - m) + ((l < 8) ? __expf(v2 - m) : 0.0f);
        #pragma unroll
        for (int msk = 1; msk < 16; msk <<= 1) e += __shfl_xor(e, msk);
        float ls = m + __logf(e);
        int cloud = base + cl;
        if (cloud < B) {
            float* op = out + (size_t)cloud * 40;
            op[l]      = v0 - ls;
            op[16 + l] = v1 - ls;
            if (l < 8) op[32 + l] = v2 - ls;
        }
    }
}

extern "C" void kernel_launch(void* const* d_in, const int* in_sizes, int n_in,
                              void* d_out, int out_size, void* d_ws, size_t ws_size,
                              hipStream_t stream) {
    const float* pos   = (const float*)d_in[0];
    const float* W     = (const float*)d_in[1];
    const float* b_dsc = (const float*)d_in[2];
    const float* w1    = (const float*)d_in[3];
    const float* b1    = (const float*)d_in[4];
    const float* w2    = (const float*)d_in[5];
    const float* b2    = (const float*)d_in[6];

    const int N = in_sizes[0] / 3;   // B*NP points
    const int B = N / NP;            // clouds

    const int grid = (B + CPB - 1) / CPB;
    fused_kernel<<<grid, T1, 0, stream>>>(pos, W, b_dsc, w1, b1, w2, b2,
                                          (float*)d_out, B);
}

// Round 20
// 29.801 us; speedup vs baseline: 1.1032x; 1.1032x over previous
//
#include <hip/hip_runtime.h>
#include <math.h>

#define NP 30      // points per cloud
#define KNN 20     // neighbors
#define KS 5       // spline control points
#define FN 10      // filter count
#define EPS 1e-8f
#define CPB 16     // clouds per block (fills the 16-row MFMA A-tile)
#define T1 512     // block size (8 waves)

typedef __attribute__((ext_vector_type(8))) short short8v;
typedef __attribute__((ext_vector_type(4))) float float4v;

__device__ __forceinline__ float satf(float x) {
    return fminf(fmaxf(x, 0.0f), 1.0f);   // folds to clamp modifier
}
__device__ __forceinline__ unsigned short bf16r(float f) {   // f32 -> bf16 RNE
    unsigned u = __float_as_uint(f);
    u += 0x7fffu + ((u >> 16) & 1u);
    return (unsigned short)(u >> 16);
}
// hA swizzle: 16B granule g of row r -> g ^ (r&7); kills stride-512B conflicts
__device__ __forceinline__ int hA_idx(int row, int col) {
    return row * 256 + ((((col >> 3) ^ (row & 7)) << 3) | (col & 7));
}
// pack point index into low 5 mantissa bits (sort stays float-compare)
__device__ __forceinline__ float packdi(float v, int j) {
    return __uint_as_float((__float_as_uint(v) & ~31u) | (unsigned)j);
}

// compare-exchange helpers (ascending / descending)
#define CEA(A, B) { float a_ = vals[A], b_ = vals[B]; vals[A] = fminf(a_, b_); vals[B] = fmaxf(a_, b_); }
#define CED(A, B) { float a_ = vals[A], b_ = vals[B]; vals[A] = fmaxf(a_, b_); vals[B] = fminf(a_, b_); }

// Fused dsc -> MLP -> log_softmax. One 512-thread block = 16 clouds.
// R20 = exact revert to R17 (best known, 29.80us). R18 (6 waves/SIMD) and
// R19 (idle-thread G,s: wave-7 divergence made it run sort+reduce serially)
// both falsified their theories; re-establishing the best state.
__global__ __launch_bounds__(T1, 4) void fused_kernel(
    const float* __restrict__ pos,     // [B*NP, 3]
    const float* __restrict__ W,       // [KS, FN]
    const float* __restrict__ b_dsc,   // [FN]
    const float* __restrict__ w1,      // [FN, 256]
    const float* __restrict__ b1,      // [256]
    const float* __restrict__ w2,      // [256, 40]
    const float* __restrict__ b2,      // [40]
    float* __restrict__ out,           // [B, 40]
    int B)
{
    __shared__ float4 ptsF[CPB * NP];                       // x,y,z,|p|^2
    __shared__ __align__(16) float sb[CPB * NP][12];        // outer-staging / sigmoid
    __shared__ __align__(16) float Gs[CPB][12];             // gxx..gzz sx sy sz
    __shared__ __align__(16) unsigned short ysbf[CPB * 40]; // bf16 ys A-tile, K-pad 40
    __shared__ __align__(16) unsigned short hA[16 * 256];   // bf16 A-tile (layer 2)
    __shared__ float Lg[CPB][48];

    const int tid  = threadIdx.x;
    const int base = blockIdx.x * CPB;
    const int w    = tid >> 6;
    const int lane = tid & 63;

    // stage: one point per thread (xyz + |p|^2)
    if (tid < CPB * NP) {
        int gp = base * NP + tid;
        if (gp < B * NP) {
            const float* pp = pos + (size_t)gp * 3;
            float x = pp[0], y = pp[1], z = pp[2];
            float n2 = fmaf(z, z, fmaf(y, y, x * x));
            ptsF[tid] = make_float4(x, y, z, n2);
        } else {
            ptsF[tid] = make_float4(0.f, 0.f, 0.f, 0.f);
        }
    }
    // zero ysbf (640 u16 = 320 u32); reduce overwrites f<10 slots after S4
    if (tid < 320) ((unsigned*)ysbf)[tid] = 0u;
    __syncthreads();                                              // S1

    const int c = tid / NP;
    const int i = tid - c * NP;
    const bool active = (tid < CPB * NP) && (base + c < B);

    float vals[32];
    float ox = 0.f, oy = 0.f, oz = 0.f, oo = 0.f;

    if (active) {
        const float4* cp = &ptsF[c * NP];
        float4 own = cp[i];                       // dynamic LDS read, once
        ox = own.x; oy = own.y; oz = own.z; oo = own.w;

        // own outer products + coords -> LDS (vectorized: 2x b128 + 1x b32)
        *(float4*)&sb[tid][0] = make_float4(ox * ox, ox * oy, ox * oz, oy * oy);
        *(float4*)&sb[tid][4] = make_float4(oy * oz, oz * oz, ox, oy);
        sb[tid][8] = oz;

        // keys: key_j = n2_j - 2 p_j.o  (3-fma form; monotone shift of d2)
        const float nx2 = -2.0f * ox, ny2 = -2.0f * oy, nz2 = -2.0f * oz;
        #pragma unroll
        for (int j = 0; j < NP; ++j) {
            float4 q = cp[j];
            float key = fmaf(q.z, nz2, fmaf(q.y, ny2, fmaf(q.x, nx2, q.w)));
            vals[j] = packdi(key, j);
            if ((j % 5) == 4) asm volatile("" ::: "memory");  // bound in-flight loads
        }
        vals[30] = packdi(1e11f, 30);
        vals[31] = packdi(1e11f, 31);

        // --- Batcher odd-even mergesort: lower 16 asc, upper 16 desc ---
        #pragma unroll
        for (int p = 1; p < 16; p <<= 1) {
            #pragma unroll
            for (int k = p; k >= 1; k >>= 1) {
                #pragma unroll
                for (int j = (k & (p - 1)); j + k < 16; j += 2 * k) {
                    #pragma unroll
                    for (int ii = 0; ii < k; ++ii) {
                        if (ii + j + k < 16 &&
                            ((ii + j) / (2 * p)) == ((ii + j + k) / (2 * p))) {
                            CEA(ii + j, ii + j + k);
                            CED(16 + ii + j, 16 + ii + j + k);
                        }
                    }
                }
            }
        }
        // --- bitonic k=32 split: BOTH sides (lower = 16-smallest SET) ---
        #pragma unroll
        for (int q = 0; q < 16; ++q) { CEA(q, 16 + q); }
        // --- bitonic merge of upper 16, pruned to the cone of 20..29 ---
        #pragma unroll
        for (int q = 0; q < 8; ++q) { CEA(16 + q, 24 + q); }
        CEA(16, 20) CEA(17, 21) CEA(18, 22) CEA(19, 23)
        CEA(24, 28) CEA(25, 29) CEA(26, 30) CEA(27, 31)
        CEA(20, 22) CEA(21, 23) CEA(24, 26) CEA(25, 27) CEA(28, 30) CEA(29, 31)
        CEA(20, 21) CEA(22, 23) CEA(24, 25) CEA(26, 27) CEA(28, 29)
    }
    __syncthreads();                                              // S2

    // G,s reduce: 144 threads (9 components x 16 clouds)
    if (tid < CPB * 9) {
        int cc   = tid / 9;
        int comp = tid - cc * 9;
        if (base + cc < B) {
            float s = 0.0f;
            #pragma unroll
            for (int k = 0; k < NP; ++k) s += sb[cc * NP + k][comp];
            Gs[cc][comp] = s;
        }
    }
    __syncthreads();                                              // S3

    if (active) {
        const float4* cp = &ptsF[c * NP];
        const float thr_key = __uint_as_float(__float_as_uint(vals[20]) & ~31u);
        const float thr_d2  = thr_key + oo;                 // rank-20 d2
        const float scale   = sqrtf(thr_d2 + EPS) + EPS;
        const float inv_s   = __builtin_amdgcn_rcpf(scale);

        // cov of ALL 30 rels from cloud G,s:  C = G - s o^T - o s^T + 30 o o^T
        float4 g0 = *(const float4*)&Gs[c][0];   // gxx gxy gxz gyy
        float4 g1 = *(const float4*)&Gs[c][4];   // gyz gzz sx  sy
        float  sx = g1.z, sy = g1.w, sz = Gs[c][8];
        float ax = fmaf(30.f, ox, -sx);
        float ay = fmaf(30.f, oy, -sy);
        float az = fmaf(30.f, oz, -sz);
        float cxx = fmaf(ox, ax, fmaf(-sx, ox, g0.x));
        float cxy = fmaf(oy, ax, fmaf(-sy, ox, g0.y));
        float cxz = fmaf(oz, ax, fmaf(-sz, ox, g0.z));
        float cyy = fmaf(oy, ay, fmaf(-sy, oy, g0.w));
        float cyz = fmaf(oz, ay, fmaf(-sz, oy, g1.x));
        float czz = fmaf(oz, az, fmaf(-sz, oz, g1.y));

        // subtract the 9 excluded outer products (ranks 21..29, sorted upper)
        #pragma unroll
        for (int q2 = 21; q2 < 30; ++q2) {
            int idx = (int)(__float_as_uint(vals[q2]) & 31u);
            float4 p = cp[idx];
            float dx = p.x - ox, dy = p.y - oy, dz = p.z - oz;
            cxx = fmaf(-dx, dx, cxx); cxy = fmaf(-dx, dy, cxy); cxz = fmaf(-dx, dz, cxz);
            cyy = fmaf(-dy, dy, cyy); cyz = fmaf(-dy, dz, cyz); czz = fmaf(-dz, dz, czz);
        }

        // power iteration x8 == C^8 v0: trace-norm + 3 symmetric squarings
        float tr = cxx + cyy + czz + 1e-30f;
        float rt = __builtin_amdgcn_rcpf(tr);
        float xx = cxx*rt, xy = cxy*rt, xz = cxz*rt;
        float yy = cyy*rt, yz = cyz*rt, zz = czz*rt;
        #pragma unroll
        for (int it = 0; it < 3; ++it) {
            float nxx = fmaf(xx, xx, fmaf(xy, xy, xz * xz));
            float nxy = fmaf(xy, xx + yy, xz * yz);
            float nxz = fmaf(xz, xx + zz, xy * yz);
            float nyy = fmaf(xy, xy, fmaf(yy, yy, yz * yz));
            float nyz = fmaf(yz, yy + zz, xy * xz);
            float nzz = fmaf(xz, xz, fmaf(yz, yz, zz * zz));
            xx = nxx; xy = nxy; xz = nxz; yy = nyy; yz = nyz; zz = nzz;
        }
        float vx = xx + xy + xz;
        float vy = xy + yy + yz;
        float vz = xz + yz + zz;
        float nn = fmaf(vz, vz, fmaf(vy, vy, vx * vx)) + 1e-30f;
        float rr2 = __builtin_amdgcn_rsqf(nn) * inv_s * 2.0f;
        const float wax = vx * rr2, way = vy * rr2, waz = vz * rr2;
        const float c0  = 2.0f - fmaf(oz, waz, fmaf(oy, way, ox * wax));

        // pass B over the 21 SELECTED points: vals[0..15] = 16-nearest set,
        // vals[16..20] = ranks 16..20. Self among them, u ~= 2 (subtracted).
        float a0 = 0.f, a1 = 0.f, a3 = 0.f, s1 = 0.f;
        #pragma unroll
        for (int q = 0; q < 21; ++q) {
            int idx = (int)(__float_as_uint(vals[q]) & 31u);
            float4 p = cp[idx];
            float ur = fmaf(p.z, waz, fmaf(p.y, way, fmaf(p.x, wax, c0)));
            a0 += satf(1.0f - ur);               // ur >= -eps: no abs needed
            a1 += satf(1.0f - fabsf(ur - 1.0f));
            a3 += satf(1.0f - fabsf(ur - 3.0f));
            s1 += ur;
            if ((q % 5) == 4) asm volatile("" ::: "memory");
        }
        const float P  = 21.0f - a0 - a1 - a3;   // a2 + a4
        const float Q  = s1 - a1 - 3.0f * a3;    // 2*a2 + 4*a4
        const float a4 = fmaf(0.5f, Q, -P);
        const float a2 = P - a4 - 1.0f;          // self sits at u=2

        // sigmoid via exp2; W/b_dsc uniform scalar loads (SGPR operands)
        #pragma unroll
        for (int f = 0; f < FN; ++f) {
            float acc = fmaf(a0, W[0*FN+f],
                        fmaf(a1, W[1*FN+f],
                        fmaf(a2, W[2*FN+f],
                        fmaf(a3, W[3*FN+f],
                             a4 * W[4*FN+f]))));
            float bn = b_dsc[f] * (-1.4426950408889634f);        // -log2e * b
            float z2 = fmaf(acc, -0.07213475204444817f, bn);     // -log2e/20
            sb[tid][f] = __builtin_amdgcn_rcpf(1.0f + exp2f(z2));
        }
    }
    __syncthreads();                                              // S4

    // ys reduce (tid<160) -> bf16 into the zero-padded A-tile
    if (tid < CPB * FN) {
        int c2 = tid / FN;
        int f  = tid - c2 * FN;
        float s = 0.0f;
        #pragma unroll
        for (int jj = 0; jj < NP; ++jj) s += sb[c2 * NP + jj][f];
        float ym = (base + c2 < B) ? s * (1.0f / (float)NP) : 0.0f;
        ysbf[c2 * 40 + f] = bf16r(ym);
    }
    __syncthreads();                                              // S5

    // layer 1 via MFMA: h[16][256] = ys[16][10pad32] @ w1[10][256] + b1; elu.
    {
        const int kg = (lane >> 4) * 8;
        short8v a = *(const short8v*)&ysbf[(lane & 15) * 40 + kg];
        #pragma unroll
        for (int t2 = 0; t2 < 2; ++t2) {
            const int n = (w * 2 + t2) * 16 + (lane & 15);
            short8v bfr;
            #pragma unroll
            for (int j = 0; j < 8; ++j) {
                int k = kg + j;
                float f = (k < FN) ? w1[k * 256 + n] : 0.0f;
                bfr[j] = (short)bf16r(f);
            }
            float4v acc = {0.f, 0.f, 0.f, 0.f};
            acc = __builtin_amdgcn_mfma_f32_16x16x32_bf16(a, bfr, acc, 0, 0, 0);
            const float bb = b1[n];
            #pragma unroll
            for (int r = 0; r < 4; ++r) {
                int cl = (lane >> 4) * 4 + r;
                float h = acc[r] + bb;
                h = h > 0.0f ? h : __expf(h) - 1.0f;
                hA[hA_idx(cl, n)] = bf16r(h);
            }
        }
    }
    __syncthreads();                                              // S6

    // layer 2: waves 0..2 each own one 16-col N-tile; B-frags global->regs.
    if (w < 3) {
        const int  n   = w * 16 + (lane & 15);
        const bool nok = n < 40;
        const int  kg  = (lane >> 4) * 8;
        float4v acc = {0.f, 0.f, 0.f, 0.f};
        #pragma unroll
        for (int s = 0; s < 8; ++s) {
            short8v bfr;
            #pragma unroll
            for (int j = 0; j < 8; ++j) {
                float f = nok ? w2[(s * 32 + kg + j) * 40 + n] : 0.0f;
                bfr[j] = (short)bf16r(f);
            }
            short8v a = *(const short8v*)&hA[hA_idx(lane & 15, kg + s * 32)];
            acc = __builtin_amdgcn_mfma_f32_16x16x32_bf16(a, bfr, acc, 0, 0, 0);
        }
        // C/D: col=lane&15 (our n), row=(lane>>4)*4+r  [m89-verified]
        if (nok) {
            const float bc = b2[n];
            const int   r0 = (lane >> 4) * 4;
            #pragma unroll
            for (int r = 0; r < 4; ++r) {
                Lg[r0 + r][n] = acc[r] + bc;
            }
        }
    }
    __syncthreads();                                              // S7

    // log_softmax: 16-lane group per cloud (tid<256)
    if (tid < CPB * 16) {
        int cl = tid >> 4, l = tid & 15;
        float v0 = Lg[cl][l];
        float v1 = Lg[cl][l + 16];
        float v2 = (l < 8) ? Lg[cl][l + 32] : -INFINITY;
        float m = fmaxf(fmaxf(v0, v1), v2);
        #pragma unroll
        for (int msk = 1; msk < 16; msk <<= 1) m = fmaxf(m, __shfl_xor(m, msk));
        float e = __expf(v0 - m) + __expf(v1 - m) + ((l < 8) ? __expf(v2 - m) : 0.0f);
        #pragma unroll
        for (int msk = 1; msk < 16; msk <<= 1) e += __shfl_xor(e, msk);
        float ls = m + __logf(e);
        int cloud = base + cl;
        if (cloud < B) {
            float* op = out + (size_t)cloud * 40;
            op[l]      = v0 - ls;
            op[16 + l] = v1 - ls;
            if (l < 8) op[32 + l] = v2 - ls;
        }
    }
}

extern "C" void kernel_launch(void* const* d_in, const int* in_sizes, int n_in,
                              void* d_out, int out_size, void* d_ws, size_t ws_size,
                              hipStream_t stream) {
    const float* pos   = (const float*)d_in[0];
    const float* W     = (const float*)d_in[1];
    const float* b_dsc = (const float*)d_in[2];
    const float* w1    = (const float*)d_in[3];
    const float* b1    = (const float*)d_in[4];
    const float* w2    = (const float*)d_in[5];
    const float* b2    = (const float*)d_in[6];

    const int N = in_sizes[0] / 3;   // B*NP points
    const int B = N / NP;            // clouds

    const int grid = (B + CPB - 1) / CPB;
    fused_kernel<<<grid, T1, 0, stream>>>(pos, W, b_dsc, w1, b1, w2, b2,
                                          (float*)d_out, B);
}